// Round 9
// baseline (530.525 us; speedup 1.0000x reference)
//
#include <hip/hip_runtime.h>

// ---------------------------------------------------------------------------
// NASNet controller, R9.
//  - Class tables h_after_0..4 (1/8/64/512/4096) precomputed (action-indep).
//  - Class decision logits fused into producer kernels (no class_logits_k).
//  - decide 0-4 = one thread/row gathering logit records.
//  - Steps 5-7: split-bf16 MFMA GEMM (K=1536 = [Ahi|Ahi|Alo]x[Bhi|Blo|Bhi]),
//    XOR-swizzled LDS; R9: 64x128 tiles, grid 1024, 4 blocks/CU for latency
//    hiding across the barrier drain (m114 mechanism).
// ---------------------------------------------------------------------------

constexpr int Bsz = 4096;
constexpr int Hsz = 512;
constexpr int G4H = 2048;

typedef unsigned short ushort_t;
using short8 = __attribute__((ext_vector_type(8))) short;
using f32x4 = __attribute__((ext_vector_type(4))) float;

struct DP {
  const float* wn[4];
  const float* bn[4];
  const float* wop;
  const float* bop;
  const float* gum;
  float* out;
  int* act;
};

__device__ __forceinline__ ushort_t f2bf_hi(float f) {
  unsigned u = __float_as_uint(f);
  u += 0x7FFF + ((u >> 16) & 1);  // RNE
  return (ushort_t)(u >> 16);
}
__device__ __forceinline__ float bf2f(ushort_t h) {
  return __uint_as_float((unsigned)h << 16);
}
__device__ __forceinline__ void glds16(const void* gsrc, void* ldst) {
  __builtin_amdgcn_global_load_lds(
      (const __attribute__((address_space(1))) void*)gsrc,
      (__attribute__((address_space(3))) void*)ldst, 16, 0, 0);
}

__device__ __forceinline__ float dotredw(const float h8[8], const float* w) {
  float4 w0 = *(const float4*)(w);
  float4 w1 = *(const float4*)(w + 4);
  float v = h8[0] * w0.x + h8[1] * w0.y + h8[2] * w0.z + h8[3] * w0.w +
            h8[4] * w1.x + h8[5] * w1.y + h8[6] * w1.z + h8[7] * w1.w;
#pragma unroll
  for (int off = 32; off > 0; off >>= 1) v += __shfl_xor(v, off, 64);
  return v;
}
__device__ __forceinline__ float dotred8(const float a[8], const float b[8]) {
  float v = a[0] * b[0] + a[1] * b[1] + a[2] * b[2] + a[3] * b[3] +
            a[4] * b[4] + a[5] * b[5] + a[6] * b[6] + a[7] * b[7];
#pragma unroll
  for (int off = 32; off > 0; off >>= 1) v += __shfl_xor(v, off, 64);
  return v;
}

__device__ __forceinline__ void lstm8(const float* Eg, const float* Gg,
                                      const float* cp, int lane, float* h8,
                                      float* c8) {
  const int j0 = lane * 8;
#pragma unroll
  for (int u = 0; u < 8; ++u) {
    int j = j0 + u;
    float iv = Eg[j], fv = Eg[512 + j], gv = Eg[1024 + j], ov = Eg[1536 + j];
    if (Gg) {
      iv += Gg[j]; fv += Gg[512 + j]; gv += Gg[1024 + j]; ov += Gg[1536 + j];
    }
    float cc = cp ? cp[j] : 0.0f;
    float ig = 1.0f / (1.0f + expf(-iv));
    float fg = 1.0f / (1.0f + expf(-fv));
    float gg = tanhf(gv);
    float og = 1.0f / (1.0f + expf(-ov));
    float cn = fg * cc + ig * gg;
    c8[u] = cn;
    h8[u] = og * tanhf(cn);
  }
}

// one class's logits (wave-uniform) -> 16-float record
__device__ __forceinline__ void class_logits_emit(
    const DP& P, const float h8[8], int lane, int s, float* Lt) {
  const int i = s >> 1;
  const int K = i + 2;
  const float* wn = P.wn[i];
  const float* bnp = P.bn[i];
  const float* wopi = P.wop + (size_t)i * (8 * Hsz);
  const float* bopi = P.bop + i * 8;
  for (int k = 0; k < K; ++k) {
    float v = dotredw(h8, wn + (size_t)k * Hsz + lane * 8);
    float nl = 2.5f * tanhf((v + bnp[k]) / 5.0f);
    if (lane == 0) Lt[k] = nl;
  }
#pragma unroll
  for (int k = 0; k < 8; ++k) {
    float v = dotredw(h8, wopi + (size_t)k * Hsz + lane * 8);
    if (lane == 0) Lt[8 + k] = (v + bopi[k]) / 5.0f;
  }
}

// full per-row wave decide (steps 5-7)
template <int K>
__device__ __forceinline__ int decide_core(const DP& P, const float h8[8],
                                           int lane, int r, int s) {
  const int i = s >> 1;
  const float* wn = P.wn[i];
  const float* bnp = P.bn[i];
  const float* wopi = P.wop + (size_t)i * (8 * Hsz);
  const float* bopi = P.bop + i * 8;
  const float* gn = P.gum + (size_t)(2 * s) * (Bsz * 8);
  const size_t SZ = (size_t)16 * Bsz;
  float* oan = P.out + (size_t)(2 * s) * Bsz;
  float* oao = oan + Bsz;
  float* oln = P.out + SZ + (size_t)(2 * s) * Bsz;
  float* olo = oln + Bsz;
  float* oen = P.out + 2 * SZ + (size_t)(2 * s) * Bsz;
  float* oeo = oen + Bsz;

  float nl[K];
#pragma unroll
  for (int k = 0; k < K; ++k) {
    float v = dotredw(h8, wn + (size_t)k * Hsz + lane * 8);
    nl[k] = 2.5f * tanhf((v + bnp[k]) / 5.0f);
  }
  float ol[8];
#pragma unroll
  for (int k = 0; k < 8; ++k) {
    float v = dotredw(h8, wopi + (size_t)k * Hsz + lane * 8);
    ol[k] = (v + bopi[k]) / 5.0f;
  }
  {
    const float* g = gn + (size_t)r * 8;
    float m = nl[0];
#pragma unroll
    for (int k = 1; k < K; ++k) m = fmaxf(m, nl[k]);
    float se = 0.0f;
#pragma unroll
    for (int k = 0; k < K; ++k) se += expf(nl[k] - m);
    float lse = logf(se);
    int a = 0;
    float best = nl[0] + g[0];
#pragma unroll
    for (int k = 1; k < K; ++k) {
      float v = nl[k] + g[k];
      if (v > best) { best = v; a = k; }
    }
    float ent = 0.0f, sel = 0.0f;
#pragma unroll
    for (int k = 0; k < K; ++k) {
      float lp = nl[k] - m - lse;
      ent -= lp * expf(lp);
      if (k == a) sel = lp;
    }
    if (lane == 0) { oan[r] = (float)a; oln[r] = sel; oen[r] = ent; }
  }
  int aop = 0;
  {
    const float* g = gn + (size_t)(Bsz * 8) + (size_t)r * 8;
    float m = ol[0];
#pragma unroll
    for (int k = 1; k < 8; ++k) m = fmaxf(m, ol[k]);
    float se = 0.0f;
#pragma unroll
    for (int k = 0; k < 8; ++k) se += expf(ol[k] - m);
    float lse = logf(se);
    float best = ol[0] + g[0];
#pragma unroll
    for (int k = 1; k < 8; ++k) {
      float v = ol[k] + g[k];
      if (v > best) { best = v; aop = k; }
    }
    float ent = 0.0f, sel = 0.0f;
#pragma unroll
    for (int k = 0; k < 8; ++k) {
      float lp = ol[k] - m - lse;
      ent -= lp * expf(lp);
      if (k == aop) sel = lp;
    }
    if (lane == 0) {
      oao[r] = (float)aop; olo[r] = sel; oeo[r] = ent; P.act[r] = aop;
    }
  }
  return aop;
}

// ---------------- K1: Wcat (block-per-row) + E/Eperm -----------------------
__global__ __launch_bounds__(256) void prep_k(
    const float* __restrict__ emb, const float* __restrict__ w_ih,
    const float* __restrict__ b_ih, const float* __restrict__ b_hh,
    const float* __restrict__ w_hh, float* __restrict__ E,
    float* __restrict__ Eperm, ushort_t* __restrict__ Wcat) {
  const int bid = blockIdx.x;
  if (bid < 2048) {
    const int ct = bid;
    const int j = ct >> 2, g = ct & 3;
    const float* sr = w_hh + (size_t)(g * 512 + j) * Hsz;
    for (int k = threadIdx.x; k < 1536; k += 256) {
      ushort_t o;
      if (k < 512) {
        o = f2bf_hi(sr[k]);
      } else if (k < 1024) {
        float x = sr[k - 512];
        ushort_t hi = f2bf_hi(x);
        o = f2bf_hi(x - bf2f(hi));
      } else {
        o = f2bf_hi(sr[k - 1024]);
      }
      Wcat[(size_t)ct * 1536 + k] = o;
    }
  } else {
    const int idx = (bid - 2048) * 256 + threadIdx.x;
    if (idx < 9 * G4H) {
      int t = idx >> 11, col = idx & 2047;
      const float* er = emb + (size_t)t * Hsz;
      const float* wr = w_ih + (size_t)col * Hsz;
      float acc = 0.0f;
      for (int k = 0; k < Hsz; k += 4) {
        float4 e = *(const float4*)(er + k);
        float4 w = *(const float4*)(wr + k);
        acc += e.x * w.x + e.y * w.y + e.z * w.z + e.w * w.w;
      }
      float v = acc + b_ih[col] + b_hh[col];
      E[idx] = v;
      int g = col >> 9, j = col & 511;
      Eperm[(size_t)t * G4H + (j << 2) + g] = v;
    }
  }
}

// ---------------- K2: G1 + pw -> h2s/c2s (8 classes) -----------------------
__global__ __launch_bounds__(256) void g1pw_k(
    const float* __restrict__ E, const float* __restrict__ w_hh,
    float* __restrict__ h2s, float* __restrict__ c2s) {
  const int lane = threadIdx.x & 63;
  const int j = (blockIdx.x << 2) + (threadIdx.x >> 6);  // 0..511
  float h8[8], c8[8];
  lstm8(E, nullptr, nullptr, lane, h8, c8);
  float c0j;
  {
    float iv = E[j], gv = E[1024 + j];
    float ig = 1.0f / (1.0f + expf(-iv));
    float gg = tanhf(gv);
    float fv = E[512 + j];
    float fg = 1.0f / (1.0f + expf(-fv));
    c0j = fg * 0.0f + ig * gg;
  }
  float gi = dotredw(h8, w_hh + (size_t)j * Hsz + lane * 8);
  float gf = dotredw(h8, w_hh + (size_t)(512 + j) * Hsz + lane * 8);
  float gg_ = dotredw(h8, w_hh + (size_t)(1024 + j) * Hsz + lane * 8);
  float go = dotredw(h8, w_hh + (size_t)(1536 + j) * Hsz + lane * 8);
  if (lane < 8) {
    int t = lane;
    const float* Eg = E + (size_t)t * G4H;
    float iv = Eg[j] + gi, fv = Eg[512 + j] + gf;
    float gv = Eg[1024 + j] + gg_, ov = Eg[1536 + j] + go;
    float ig = 1.0f / (1.0f + expf(-iv));
    float fg = 1.0f / (1.0f + expf(-fv));
    float gg = tanhf(gv);
    float og = 1.0f / (1.0f + expf(-ov));
    float cn = fg * c0j + ig * gg;
    c2s[t * 512 + j] = cn;
    h2s[t * 512 + j] = og * tanhf(cn);
  }
}

// ---------------- K3: G2 + pw -> h3s/c3s (64 classes) + L0/L1 logits -------
__global__ __launch_bounds__(256) void g2pw_k(
    DP P, const float* __restrict__ E, const float* __restrict__ w_hh,
    const float* __restrict__ h2s, const float* __restrict__ c2s,
    float* __restrict__ h3s, float* __restrict__ c3s,
    float* __restrict__ Ltab) {
  const int lane = threadIdx.x & 63;
  if (blockIdx.x >= 512) {  // L0 (1 class from E) + L1 (8 classes from h2s)
    const int w = ((blockIdx.x - 512) << 2) + (threadIdx.x >> 6);
    if (w >= 9) return;
    float h8[8];
    if (w == 0) {
      float c8[8];
      lstm8(E, nullptr, nullptr, lane, h8, c8);
      class_logits_emit(P, h8, lane, 0, Ltab);
    } else {
      const float* hr = h2s + (size_t)(w - 1) * 512 + lane * 8;
      float4 a0 = *(const float4*)hr, a1 = *(const float4*)(hr + 4);
      h8[0] = a0.x; h8[1] = a0.y; h8[2] = a0.z; h8[3] = a0.w;
      h8[4] = a1.x; h8[5] = a1.y; h8[6] = a1.z; h8[7] = a1.w;
      class_logits_emit(P, h8, lane, 1, Ltab + (size_t)w * 16);
    }
    return;
  }
  const int wid = (blockIdx.x << 2) + (threadIdx.x >> 6);  // 0..2047
  for (int task = wid; task < 8 * 512; task += 2048) {
    int q = task >> 9, j = task & 511;
    float h8[8];
    const float* hr = h2s + (size_t)q * 512 + lane * 8;
    float4 a0 = *(const float4*)hr, a1 = *(const float4*)(hr + 4);
    h8[0] = a0.x; h8[1] = a0.y; h8[2] = a0.z; h8[3] = a0.w;
    h8[4] = a1.x; h8[5] = a1.y; h8[6] = a1.z; h8[7] = a1.w;
    float gi = dotredw(h8, w_hh + (size_t)j * Hsz + lane * 8);
    float gf = dotredw(h8, w_hh + (size_t)(512 + j) * Hsz + lane * 8);
    float gg_ = dotredw(h8, w_hh + (size_t)(1024 + j) * Hsz + lane * 8);
    float go = dotredw(h8, w_hh + (size_t)(1536 + j) * Hsz + lane * 8);
    float cpj = c2s[q * 512 + j];
    if (lane < 8) {
      int t = lane;
      const float* Eg = E + (size_t)t * G4H;
      float iv = Eg[j] + gi, fv = Eg[512 + j] + gf;
      float gv = Eg[1024 + j] + gg_, ov = Eg[1536 + j] + go;
      float ig = 1.0f / (1.0f + expf(-iv));
      float fg = 1.0f / (1.0f + expf(-fv));
      float gg = tanhf(gv);
      float og = 1.0f / (1.0f + expf(-ov));
      float cn = fg * cpj + ig * gg;
      c3s[(q * 8 + t) * 512 + j] = cn;
      h3s[(q * 8 + t) * 512 + j] = og * tanhf(cn);
    }
  }
}

// ---------------- K4: G3 + pw -> h4s/c4s (512 classes) + L2 logits ---------
__global__ __launch_bounds__(256) void g3pw_k(
    DP P, const float* __restrict__ E, const float* __restrict__ w_hh,
    const float* __restrict__ h3s, const float* __restrict__ c3s,
    float* __restrict__ h4s, float* __restrict__ c4s,
    float* __restrict__ Ltab) {
  const int lane = threadIdx.x & 63;
  if (blockIdx.x >= 512) {  // L2: 64 classes from h3s
    const int w = ((blockIdx.x - 512) << 2) + (threadIdx.x >> 6);
    if (w >= 64) return;
    const float* hr = h3s + (size_t)w * 512 + lane * 8;
    float4 a0 = *(const float4*)hr, a1 = *(const float4*)(hr + 4);
    float h8[8] = {a0.x, a0.y, a0.z, a0.w, a1.x, a1.y, a1.z, a1.w};
    class_logits_emit(P, h8, lane, 2, Ltab + (size_t)(9 + w) * 16);
    return;
  }
  const int gw = (blockIdx.x << 2) + (threadIdx.x >> 6);  // 0..2047
  const int j = gw >> 2, qg = gw & 3;
  float wi[8], wf[8], wg[8], wo[8];
  {
    const float* w0 = w_hh + (size_t)j * Hsz + lane * 8;
    const float* w1 = w_hh + (size_t)(512 + j) * Hsz + lane * 8;
    const float* w2 = w_hh + (size_t)(1024 + j) * Hsz + lane * 8;
    const float* w3 = w_hh + (size_t)(1536 + j) * Hsz + lane * 8;
#pragma unroll
    for (int u = 0; u < 8; ++u) {
      wi[u] = w0[u]; wf[u] = w1[u]; wg[u] = w2[u]; wo[u] = w3[u];
    }
  }
  for (int q = qg * 16; q < qg * 16 + 16; ++q) {
    float h8[8];
    const float* hr = h3s + (size_t)q * 512 + lane * 8;
    float4 a0 = *(const float4*)hr, a1 = *(const float4*)(hr + 4);
    h8[0] = a0.x; h8[1] = a0.y; h8[2] = a0.z; h8[3] = a0.w;
    h8[4] = a1.x; h8[5] = a1.y; h8[6] = a1.z; h8[7] = a1.w;
    float gi = dotred8(h8, wi);
    float gf = dotred8(h8, wf);
    float gg_ = dotred8(h8, wg);
    float go = dotred8(h8, wo);
    float cpj = c3s[q * 512 + j];
    if (lane < 8) {
      int t = lane;
      const float* Eg = E + (size_t)t * G4H;
      float iv = Eg[j] + gi, fv = Eg[512 + j] + gf;
      float gv = Eg[1024 + j] + gg_, ov = Eg[1536 + j] + go;
      float ig = 1.0f / (1.0f + expf(-iv));
      float fg = 1.0f / (1.0f + expf(-fv));
      float gg = tanhf(gv);
      float og = 1.0f / (1.0f + expf(-ov));
      float cn = fg * cpj + ig * gg;
      c4s[(q * 8 + t) * 512 + j] = cn;
      h4s[(q * 8 + t) * 512 + j] = og * tanhf(cn);
    }
  }
}

// ---------------- K5: gemm64 (G4 = h4s @ w_hh^T) + L3 logits ---------------
__global__ __launch_bounds__(256) void gemm64(
    DP P, const float* __restrict__ A, const float* __restrict__ Bw,
    float* __restrict__ G, const float* __restrict__ h4s,
    float* __restrict__ Ltab) {
  if (blockIdx.x >= 256) {  // L3: 512 classes from h4s
    const int lane = threadIdx.x & 63;
    const int w = ((blockIdx.x - 256) << 2) + (threadIdx.x >> 6);
    if (w >= 512) return;
    const float* hr = h4s + (size_t)w * 512 + lane * 8;
    float4 a0 = *(const float4*)hr, a1 = *(const float4*)(hr + 4);
    float h8[8] = {a0.x, a0.y, a0.z, a0.w, a1.x, a1.y, a1.z, a1.w};
    class_logits_emit(P, h8, lane, 3, Ltab + (size_t)(73 + w) * 16);
    return;
  }
  constexpr int LDA = 68;
  __shared__ float As[16 * LDA];
  __shared__ float Bs[16 * LDA];
  const int tid = threadIdx.x;
  const int bx = blockIdx.x & 31;
  const int by = blockIdx.x >> 5;
  const int r0 = by * 64, c0 = bx * 64;
  const int tx = tid & 15, ty = tid >> 4;
  const int lr = tid >> 2;
  const int lk = (tid & 3) << 2;
  const float* Ar = A + (size_t)(r0 + lr) * Hsz;
  const float* Br = Bw + (size_t)(c0 + lr) * Hsz;
  float acc[4][4];
#pragma unroll
  for (int i = 0; i < 4; ++i)
#pragma unroll
    for (int j = 0; j < 4; ++j) acc[i][j] = 0.0f;

  for (int k0 = 0; k0 < Hsz; k0 += 16) {
    float4 a = *(const float4*)(Ar + k0 + lk);
    float4 b = *(const float4*)(Br + k0 + lk);
    __syncthreads();
    As[(lk + 0) * LDA + lr] = a.x;
    As[(lk + 1) * LDA + lr] = a.y;
    As[(lk + 2) * LDA + lr] = a.z;
    As[(lk + 3) * LDA + lr] = a.w;
    Bs[(lk + 0) * LDA + lr] = b.x;
    Bs[(lk + 1) * LDA + lr] = b.y;
    Bs[(lk + 2) * LDA + lr] = b.z;
    Bs[(lk + 3) * LDA + lr] = b.w;
    __syncthreads();
#pragma unroll
    for (int kk = 0; kk < 16; ++kk) {
      float4 av = *(const float4*)&As[kk * LDA + (ty << 2)];
      float4 bv = *(const float4*)&Bs[kk * LDA + (tx << 2)];
      float avs[4] = {av.x, av.y, av.z, av.w};
      float bvs[4] = {bv.x, bv.y, bv.z, bv.w};
#pragma unroll
      for (int i = 0; i < 4; ++i)
#pragma unroll
        for (int j = 0; j < 4; ++j) acc[i][j] = fmaf(avs[i], bvs[j], acc[i][j]);
    }
  }
#pragma unroll
  for (int i = 0; i < 4; ++i)
#pragma unroll
    for (int j = 0; j < 4; ++j)
      G[(size_t)(r0 + (ty << 2) + i) * G4H + c0 + (tx << 2) + j] = acc[i][j];
}

// ---------------- K6: h_after_4 table (4096) + Acat5c + L4 logits ----------
__global__ __launch_bounds__(256) void pw5c_k(
    DP P, const float* __restrict__ E, const float* __restrict__ G4raw,
    const float* __restrict__ c4s, float* __restrict__ c5c,
    ushort_t* __restrict__ Acat5c, float* __restrict__ Ltab4) {
  const int lane = threadIdx.x & 63;
  const int q4 = (blockIdx.x << 2) + (threadIdx.x >> 6);  // 0..4095
  const int q3 = q4 >> 3, t = q4 & 7;
  float h8[8], c8[8];
  lstm8(E + (size_t)t * G4H, G4raw + (size_t)q3 * G4H, c4s + (size_t)q3 * 512,
        lane, h8, c8);
#pragma unroll
  for (int u = 0; u < 8; ++u) {
    int j = lane * 8 + u;
    c5c[(size_t)q4 * 512 + j] = c8[u];
    ushort_t hi = f2bf_hi(h8[u]);
    Acat5c[(size_t)q4 * 1024 + j] = hi;
    Acat5c[(size_t)q4 * 1024 + 512 + j] = f2bf_hi(h8[u] - bf2f(hi));
  }
  class_logits_emit(P, h8, lane, 4, Ltab4 + (size_t)q4 * 16);
}

// ---------------- K7: decides 0-4, one thread per row ----------------------
__global__ __launch_bounds__(256) void decide_early_k(
    DP P, const float* __restrict__ Ltab, int* __restrict__ q4arr) {
  const int r = blockIdx.x * 256 + threadIdx.x;
  if (r >= Bsz) return;
  const size_t SZ = (size_t)16 * Bsz;
  const int Ks[5] = {2, 2, 3, 3, 4};
  const int base[5] = {0, 1, 9, 73, 585};
  int q = 0;
  int aop = 0;
#pragma unroll
  for (int s = 0; s < 5; ++s) {
    const int K = Ks[s];
    const float* Lt = Ltab + (size_t)(base[s] + q) * 16;
    const float* gn = P.gum + (size_t)(2 * s) * (Bsz * 8);
    float* oan = P.out + (size_t)(2 * s) * Bsz;
    float* oao = oan + Bsz;
    float* oln = P.out + SZ + (size_t)(2 * s) * Bsz;
    float* olo = oln + Bsz;
    float* oen = P.out + 2 * SZ + (size_t)(2 * s) * Bsz;
    float* oeo = oen + Bsz;
    {
      float nl[5];
      for (int k = 0; k < K; ++k) nl[k] = Lt[k];
      const float* g = gn + (size_t)r * 8;
      float m = nl[0];
      for (int k = 1; k < K; ++k) m = fmaxf(m, nl[k]);
      float se = 0.0f;
      for (int k = 0; k < K; ++k) se += expf(nl[k] - m);
      float lse = logf(se);
      int a = 0;
      float best = nl[0] + g[0];
      for (int k = 1; k < K; ++k) {
        float v = nl[k] + g[k];
        if (v > best) { best = v; a = k; }
      }
      float ent = 0.0f, sel = 0.0f;
      for (int k = 0; k < K; ++k) {
        float lp = nl[k] - m - lse;
        ent -= lp * expf(lp);
        if (k == a) sel = lp;
      }
      oan[r] = (float)a; oln[r] = sel; oen[r] = ent;
    }
    {
      float ol[8];
#pragma unroll
      for (int k = 0; k < 8; ++k) ol[k] = Lt[8 + k];
      const float* g = gn + (size_t)(Bsz * 8) + (size_t)r * 8;
      float m = ol[0];
#pragma unroll
      for (int k = 1; k < 8; ++k) m = fmaxf(m, ol[k]);
      float se = 0.0f;
#pragma unroll
      for (int k = 0; k < 8; ++k) se += expf(ol[k] - m);
      float lse = logf(se);
      aop = 0;
      float best = ol[0] + g[0];
#pragma unroll
      for (int k = 1; k < 8; ++k) {
        float v = ol[k] + g[k];
        if (v > best) { best = v; aop = k; }
      }
      float ent = 0.0f, sel = 0.0f;
#pragma unroll
      for (int k = 0; k < 8; ++k) {
        float lp = ol[k] - m - lse;
        ent -= lp * expf(lp);
        if (k == aop) sel = lp;
      }
      oao[r] = (float)aop; olo[r] = sel; oeo[r] = ent;
    }
    if (s < 4) q = q * 8 + aop;
  }
  q4arr[r] = q;
  P.act[r] = aop;
}

// ---------------- split-bf16 MFMA GEMM + fused LSTM pointwise --------------
// R9: 64x128 tiles, grid 1024 (64 row-tiles x 16 ct-col-tiles), 4 blocks/CU.
__global__ __launch_bounds__(256, 4) void gemm_bf16_lstm(
    const ushort_t* __restrict__ Acat, const ushort_t* __restrict__ Wcat,
    const float* __restrict__ Eperm, const int* __restrict__ act,
    const int* __restrict__ qmap, const float* __restrict__ ctab,
    float* __restrict__ cF, float* __restrict__ h_out,
    ushort_t* __restrict__ Aout) {
  __shared__ union {
    struct { ushort_t A[64 * 64]; ushort_t B[128 * 64]; } s;  // 24 KB
    float C[64 * 132];                                        // 33.8 KB
  } sm;

  const int tid = threadIdx.x;
  const int wave = tid >> 6, lane = tid & 63;
  const int bx = blockIdx.x & 15;   // ct col tile (128 wide)
  const int by = blockIdx.x >> 4;   // row tile (64 rows)
  const int r0 = by * 64, c0 = bx * 128;
  const int wr = (wave >> 1) * 32, wc = (wave & 1) * 64;
  const int mrow = lane & 15, quad = lane >> 4;
  const int slr = lane >> 3;
  const int ssw = ((lane & 7) ^ slr) << 3;

  // A rows this lane stages (regions g<8 are A: g = q2*4+wave for q2<2)
  int arow[2];
#pragma unroll
  for (int q2 = 0; q2 < 2; ++q2) {
    const int lrow = r0 + (q2 * 4 + wave) * 8 + slr;
    arow[q2] = qmap ? qmap[lrow] : lrow;
  }

  f32x4 acc[2][4];
#pragma unroll
  for (int i = 0; i < 2; ++i)
#pragma unroll
    for (int jt = 0; jt < 4; ++jt) acc[i][jt] = (f32x4){0.f, 0.f, 0.f, 0.f};

  for (int k0 = 0; k0 < 1536; k0 += 64) {
    const int ak = (k0 < 512) ? k0 : k0 - 512;  // A dup-block remap
    __syncthreads();
#pragma unroll
    for (int q2 = 0; q2 < 6; ++q2) {  // 24 regions of 1 KB (8 A + 16 B)
      const int g = q2 * 4 + wave;
      if (g < 8) {
        glds16(Acat + (size_t)arow[q2] * 1024 + ak + ssw,
               (char*)sm.s.A + g * 1024);
      } else {
        const int row = c0 + (g - 8) * 8 + slr;
        glds16(Wcat + (size_t)row * 1536 + k0 + ssw,
               (char*)sm.s.B + (g - 8) * 1024);
      }
    }
    __syncthreads();
#pragma unroll
    for (int kk = 0; kk < 2; ++kk) {
      const int swr2 = ((kk * 4 + quad) ^ (mrow & 7)) << 3;
      short8 a[2], b[4];
#pragma unroll
      for (int i = 0; i < 2; ++i)
        a[i] = *(const short8*)&sm.s.A[(wr + i * 16 + mrow) * 64 + swr2];
#pragma unroll
      for (int jt = 0; jt < 4; ++jt)
        b[jt] = *(const short8*)&sm.s.B[(wc + jt * 16 + mrow) * 64 + swr2];
#pragma unroll
      for (int i = 0; i < 2; ++i)
#pragma unroll
        for (int jt = 0; jt < 4; ++jt)
          acc[i][jt] = __builtin_amdgcn_mfma_f32_16x16x32_bf16(
              a[i], b[jt], acc[i][jt], 0, 0, 0);
    }
  }

  // ---- epilogue: single-phase C through LDS, fused LSTM pointwise ----
  __syncthreads();  // K-loop LDS reads done before overwrite
#pragma unroll
  for (int i = 0; i < 2; ++i)
#pragma unroll
    for (int jt = 0; jt < 4; ++jt)
#pragma unroll
      for (int rg = 0; rg < 4; ++rg)
        sm.C[(wr + i * 16 + quad * 4 + rg) * 132 + wc + jt * 16 + mrow] =
            acc[i][jt][rg];
  __syncthreads();
  const int jj = tid & 31;
  const int rbase = tid >> 5;
#pragma unroll
  for (int rp = 0; rp < 8; ++rp) {
    const int rl = rbase * 8 + rp;  // 0..63
    const int grow = r0 + rl;
    float4 g4 = *(float4*)&sm.C[rl * 132 + jj * 4];
    const int a = act[grow];
    const int jglob = (c0 >> 2) + jj;
    float4 e4 = *(const float4*)&Eperm[(size_t)a * G4H + c0 + jj * 4];
    float iv = g4.x + e4.x, fv = g4.y + e4.y;
    float gv = g4.z + e4.z, ov = g4.w + e4.w;
    float ig = 1.0f / (1.0f + expf(-iv));
    float fg = 1.0f / (1.0f + expf(-fv));
    float gg = tanhf(gv);
    float og = 1.0f / (1.0f + expf(-ov));
    float cp;
    if (qmap) {
      cp = ctab[(size_t)qmap[grow] * Hsz + jglob];
    } else {
      cp = cF[(size_t)grow * Hsz + jglob];
    }
    float cn = fg * cp + ig * gg;
    float hn = og * tanhf(cn);
    const size_t ci = (size_t)grow * Hsz + jglob;
    cF[ci] = cn;
    h_out[ci] = hn;
    if (Aout) {
      ushort_t hi = f2bf_hi(hn);
      Aout[(size_t)grow * 1024 + jglob] = hi;
      Aout[(size_t)grow * 1024 + 512 + jglob] = f2bf_hi(hn - bf2f(hi));
    }
  }
}

// ---------------- decide for steps 5-7 (per-row h from hA) -----------------
template <int K>
__global__ __launch_bounds__(256) void decide_late_k(DP P,
                                                     const float* __restrict__ hA,
                                                     int s) {
  const int lane = threadIdx.x & 63;
  const int r = (blockIdx.x << 2) + (threadIdx.x >> 6);
  const float* hr = hA + (size_t)r * Hsz + lane * 8;
  float4 a0 = *(const float4*)hr, a1 = *(const float4*)(hr + 4);
  float h8[8] = {a0.x, a0.y, a0.z, a0.w, a1.x, a1.y, a1.z, a1.w};
  decide_core<K>(P, h8, lane, r, s);
}

// ---------------------------------------------------------------------------
extern "C" void kernel_launch(void* const* d_in, const int* in_sizes, int n_in,
                              void* d_out, int out_size, void* d_ws,
                              size_t ws_size, hipStream_t stream) {
  (void)in_sizes; (void)n_in; (void)out_size; (void)ws_size;
  const float* emb = (const float*)d_in[0];
  const float* w_ih = (const float*)d_in[1];
  const float* w_hh = (const float*)d_in[2];
  const float* b_ih = (const float*)d_in[3];
  const float* b_hh = (const float*)d_in[4];

  DP P;
  P.wn[0] = (const float*)d_in[5];  P.bn[0] = (const float*)d_in[6];
  P.wn[1] = (const float*)d_in[7];  P.bn[1] = (const float*)d_in[8];
  P.wn[2] = (const float*)d_in[9];  P.bn[2] = (const float*)d_in[10];
  P.wn[3] = (const float*)d_in[11]; P.bn[3] = (const float*)d_in[12];
  P.wop = (const float*)d_in[13];
  P.bop = (const float*)d_in[14];
  P.gum = (const float*)d_in[15];
  P.out = (float*)d_out;

  float* ws = (float*)d_ws;
  float* E = ws;      ws += 9 * G4H;
  float* Eperm = ws;  ws += 9 * G4H;
  float* h2s = ws;    ws += 8 * Hsz;
  float* c2s = ws;    ws += 8 * Hsz;
  float* h3s = ws;    ws += 64 * Hsz;
  float* c3s = ws;    ws += 64 * Hsz;
  float* h4s = ws;    ws += 512 * Hsz;
  float* c4s = ws;    ws += 512 * Hsz;
  float* G4raw = ws;  ws += 512 * G4H;
  float* c5c = ws;    ws += (size_t)Bsz * Hsz;
  float* hA = ws;     ws += (size_t)Bsz * Hsz;
  float* cF = ws;     ws += (size_t)Bsz * Hsz;
  float* Ltab = ws;   ws += (size_t)(585 + 4096) * 16;
  ushort_t* AcatQ = (ushort_t*)ws; ws += (size_t)Bsz * 1024 / 2;
  ushort_t* AcatP = (ushort_t*)ws; ws += (size_t)Bsz * 1024 / 2;
  ushort_t* Wcat = (ushort_t*)ws;  ws += (size_t)2048 * 1536 / 2;
  int* act = (int*)ws;
  int* q4arr = act + Bsz;
  P.act = act;
  float* Ltab4 = Ltab + (size_t)585 * 16;

  prep_k<<<2120, 256, 0, stream>>>(emb, w_ih, b_ih, b_hh, w_hh, E, Eperm, Wcat);
  g1pw_k<<<128, 256, 0, stream>>>(E, w_hh, h2s, c2s);
  g2pw_k<<<515, 256, 0, stream>>>(P, E, w_hh, h2s, c2s, h3s, c3s, Ltab);
  g3pw_k<<<528, 256, 0, stream>>>(P, E, w_hh, h3s, c3s, h4s, c4s, Ltab);
  gemm64<<<384, 256, 0, stream>>>(P, h4s, w_hh, G4raw, h4s, Ltab);
  pw5c_k<<<1024, 256, 0, stream>>>(P, E, G4raw, c4s, c5c, AcatQ, Ltab4);
  decide_early_k<<<16, 256, 0, stream>>>(P, Ltab, q4arr);
  // step 5: gather-A GEMM (rows = class q4[r]), c from c5c table
  gemm_bf16_lstm<<<1024, 256, 0, stream>>>(AcatQ, Wcat, Eperm, act, q4arr, c5c,
                                           cF, hA, AcatP);
  decide_late_k<4><<<Bsz / 4, 256, 0, stream>>>(P, hA, 5);
  // step 6
  gemm_bf16_lstm<<<1024, 256, 0, stream>>>(AcatP, Wcat, Eperm, act, nullptr,
                                           nullptr, cF, hA, AcatQ);
  decide_late_k<5><<<Bsz / 4, 256, 0, stream>>>(P, hA, 6);
  // step 7: no Aout needed
  gemm_bf16_lstm<<<1024, 256, 0, stream>>>(AcatQ, Wcat, Eperm, act, nullptr,
                                           nullptr, cF, hA, nullptr);
  decide_late_k<5><<<Bsz / 4, 256, 0, stream>>>(P, hA, 7);
}